// Round 1
// baseline (255.200 us; speedup 1.0000x reference)
//
#include <hip/hip_runtime.h>
#include <hip/hip_fp16.h>

typedef __attribute__((ext_vector_type(4))) float f32x4;
typedef __attribute__((ext_vector_type(8))) _Float16 h8;
typedef __attribute__((ext_vector_type(4))) _Float16 h4;

// ---------------------------------------------------------------- helpers
__device__ __forceinline__ void gld16(const _Float16* g, _Float16* l) {
  __builtin_amdgcn_global_load_lds(
      (const __attribute__((address_space(1))) void*)g,
      (__attribute__((address_space(3))) void*)l, 16, 0, 0);
}

// ---------------------------------------------------------------- convert f32 -> f16 (vectorized)
__global__ void cvt_f32_h(const float* __restrict__ in, _Float16* __restrict__ out, int n8) {
  for (int i = blockIdx.x * blockDim.x + threadIdx.x; i < n8; i += gridDim.x * blockDim.x) {
    const f32x4* p = (const f32x4*)(in + (size_t)i * 8);
    f32x4 a = p[0], b = p[1];
    h8 o;
    o[0] = (_Float16)a[0]; o[1] = (_Float16)a[1]; o[2] = (_Float16)a[2]; o[3] = (_Float16)a[3];
    o[4] = (_Float16)b[0]; o[5] = (_Float16)b[1]; o[6] = (_Float16)b[2]; o[7] = (_Float16)b[3];
    *(h8*)(out + (size_t)i * 8) = o;
  }
}

// ---------------------------------------------------------------- transpose + convert: in[R][C] f32 -> out[C][R] f16
__global__ void transpose_cvt(const float* __restrict__ in, _Float16* __restrict__ out, int R, int C) {
  __shared__ float tile[32][33];
  const int tx = threadIdx.x & 31, ty = threadIdx.x >> 5;  // 256 thr: ty 0..7
  const int c = blockIdx.x * 32 + tx;
#pragma unroll
  for (int j = 0; j < 32; j += 8) {
    int r = blockIdx.y * 32 + ty + j;
    tile[ty + j][tx] = in[(size_t)r * C + c];
  }
  __syncthreads();
#pragma unroll
  for (int j = 0; j < 32; j += 8) {
    out[(size_t)(blockIdx.x * 32 + ty + j) * R + blockIdx.y * 32 + tx] = (_Float16)tile[tx][ty + j];
  }
}

// ---------------------------------------------------------------- GEMM: C[M][Nn] = A[M][K] * Bt[Nn][K]^T
// m97 structure: 128x128 tile, BK=64, 256 thr (4 waves 2x2), mfma_f32_16x16x32_f16
// EPI 0: scatter to q/k/v fp16 buffers (Q scaled).  EPI 1: f32 out + bias.
template <int EPI>
__global__ __launch_bounds__(256, 2)
void gemm_kernel(const _Float16* __restrict__ A, const _Float16* __restrict__ Bt,
                 float* __restrict__ outF, const float* __restrict__ bias,
                 _Float16* __restrict__ q_h, _Float16* __restrict__ k_h,
                 _Float16* __restrict__ v_t, const int Nn, const int K) {
  __shared__ _Float16 As[128 * 64];
  __shared__ _Float16 Bs[128 * 64];
  const int tid = threadIdx.x;
  const int wid = tid >> 6, lane = tid & 63;
  const int g = lane >> 4, r16 = lane & 15;
  const int wr = wid >> 1, wc = wid & 1;
  const int row0 = blockIdx.x * 128;
  const int col0 = blockIdx.y * 128;
  f32x4 acc[4][4] = {};
  const int sr = tid >> 3, sc = tid & 7;
  const _Float16* ag = A + (size_t)(row0 + sr) * K + sc * 8;
  const _Float16* bg = Bt + (size_t)(col0 + sr) * K + sc * 8;

  for (int kt = 0; kt < K; kt += 64) {
    __syncthreads();
#pragma unroll
    for (int i = 0; i < 4; ++i)
      gld16(ag + (size_t)i * 32 * K + kt, As + i * 2048 + wid * 512);
#pragma unroll
    for (int i = 0; i < 4; ++i)
      gld16(bg + (size_t)i * 32 * K + kt, Bs + i * 2048 + wid * 512);
    __syncthreads();

#pragma unroll
    for (int kk = 0; kk < 2; ++kk) {
      h8 af[4], bf[4];
#pragma unroll
      for (int mt = 0; mt < 4; ++mt)
        af[mt] = *(const h8*)(As + (wr * 64 + mt * 16 + r16) * 64 + kk * 32 + g * 8);
#pragma unroll
      for (int nt = 0; nt < 4; ++nt)
        bf[nt] = *(const h8*)(Bs + (wc * 64 + nt * 16 + r16) * 64 + kk * 32 + g * 8);
#pragma unroll
      for (int mt = 0; mt < 4; ++mt)
#pragma unroll
        for (int nt = 0; nt < 4; ++nt)
          acc[mt][nt] = __builtin_amdgcn_mfma_f32_16x16x32_f16(af[mt], bf[nt], acc[mt][nt], 0, 0, 0);
    }
  }

  if (EPI == 0) {
    const float qscale = 0.125f * 1.44269504088896340736f;  // 1/sqrt(64) * log2(e)
#pragma unroll
    for (int mt = 0; mt < 4; ++mt) {
#pragma unroll
      for (int nt = 0; nt < 4; ++nt) {
        const int j = col0 + wc * 64 + nt * 16 + r16;
        const int which = j >> 10;
        const int hd = j & 1023;
        const int hh = hd >> 6, dd = hd & 63;
#pragma unroll
        for (int rg = 0; rg < 4; ++rg) {
          const int mm = row0 + wr * 64 + mt * 16 + g * 4 + rg;
          const int b = mm >> 11, n = mm & 2047;
          const size_t bh = (size_t)(b * 16 + hh);
          const float v = acc[mt][nt][rg];
          if (which == 0)      q_h[(bh * 2048 + n) * 64 + dd] = (_Float16)(v * qscale);
          else if (which == 1) k_h[(bh * 2048 + n) * 64 + dd] = (_Float16)v;
          else                 v_t[(bh * 64 + dd) * 2048 + n] = (_Float16)v;
        }
      }
    }
  } else {
#pragma unroll
    for (int mt = 0; mt < 4; ++mt) {
#pragma unroll
      for (int nt = 0; nt < 4; ++nt) {
        const int j = col0 + wc * 64 + nt * 16 + r16;
        const float bv = bias[j];
#pragma unroll
        for (int rg = 0; rg < 4; ++rg) {
          const int mm = row0 + wr * 64 + mt * 16 + g * 4 + rg;
          outF[(size_t)mm * Nn + j] = acc[mt][nt][rg] + bv;
        }
      }
    }
  }
}

// ---------------------------------------------------------------- flash attention
// Q,K: [bh][2048][64] f16 (Q pre-scaled by 1/8*log2e).  Vt: [bh][64][2048] f16.
// O: [b][n][h*64+d] f16.  Per block: one (bh, 64-row q-tile); 4 waves x 16 q-rows.
// S^T = mfma(K, Q) so softmax rows are lane-local; PV via 16x16x16 (P^T C-frag == B-frag layout).
__global__ __launch_bounds__(256, 2)
void attn_kernel(const _Float16* __restrict__ Qall, const _Float16* __restrict__ Kall,
                 const _Float16* __restrict__ Vtall, _Float16* __restrict__ Oall) {
  __shared__ _Float16 Qs[64 * 64];
  __shared__ _Float16 Ks[64 * 64];
  __shared__ _Float16 Vs[64 * 64];
  const int tid = threadIdx.x;
  const int wid = tid >> 6, lane = tid & 63;
  const int g = lane >> 4, r16 = lane & 15;
  const int blk = blockIdx.x;
  const int qt = blk & 31;       // fast dim: q-tiles share (b,h) KV in L2
  const int bh = blk >> 5;
  const _Float16* Qg = Qall + (size_t)bh * (2048 * 64);
  const _Float16* Kg = Kall + (size_t)bh * (2048 * 64);
  const _Float16* Vg = Vtall + (size_t)bh * (2048 * 64);
  const int q0 = qt * 64;
  const int sr = tid >> 3, sc = tid & 7;

  // stage Q tile [64 rows][64 d], XOR-swizzled source so swizzled reads work
#pragma unroll
  for (int i = 0; i < 2; ++i) {
    int r = i * 32 + sr;
    gld16(Qg + (size_t)(q0 + r) * 64 + ((sc ^ (r & 7)) << 3), Qs + i * 2048 + wid * 512);
  }
  __syncthreads();

  const int qrow = wid * 16 + r16;
  const int qsw = qrow & 7;
  const h8 qf0 = *(const h8*)(Qs + qrow * 64 + ((g ^ qsw) << 3));
  const h8 qf1 = *(const h8*)(Qs + qrow * 64 + (((g + 4) ^ qsw) << 3));

  f32x4 ot[4] = {};
  float m = -3.0e38f, lsum = 0.f;

  for (int t = 0; t < 32; ++t) {
    const int kv0 = t * 64;
    __syncthreads();
#pragma unroll
    for (int i = 0; i < 2; ++i) {
      int r = i * 32 + sr;
      gld16(Kg + (size_t)(kv0 + r) * 64 + ((sc ^ (r & 7)) << 3), Ks + i * 2048 + wid * 512);
    }
#pragma unroll
    for (int i = 0; i < 2; ++i) {
      int r = i * 32 + sr;  // r = d row of Vt
      gld16(Vg + (size_t)r * 2048 + kv0 + ((sc ^ (r & 7)) << 3), Vs + i * 2048 + wid * 512);
    }
    __syncthreads();

    // S^T[key][q] for 64 keys: 4 frags of 16 keys
    f32x4 st[4];
#pragma unroll
    for (int f = 0; f < 4; ++f) {
      const int krow = f * 16 + r16;
      const int ks = krow & 7;
      h8 ka0 = *(const h8*)(Ks + krow * 64 + ((g ^ ks) << 3));
      h8 ka1 = *(const h8*)(Ks + krow * 64 + (((g + 4) ^ ks) << 3));
      f32x4 s = {};
      s = __builtin_amdgcn_mfma_f32_16x16x32_f16(ka0, qf0, s, 0, 0, 0);
      s = __builtin_amdgcn_mfma_f32_16x16x32_f16(ka1, qf1, s, 0, 0, 0);
      st[f] = s;
    }

    // online softmax (exp2 domain; scale folded into Q). Lane q = qrow.
    float pmax = st[0][0];
#pragma unroll
    for (int f = 0; f < 4; ++f)
#pragma unroll
      for (int rg = 0; rg < 4; ++rg) pmax = fmaxf(pmax, st[f][rg]);
    pmax = fmaxf(pmax, __shfl_xor(pmax, 16));
    pmax = fmaxf(pmax, __shfl_xor(pmax, 32));
    const float mnew = fmaxf(m, pmax);
    const float corr = __builtin_amdgcn_exp2f(m - mnew);
    m = mnew;
    float rs = 0.f;
    h4 pb[4];
#pragma unroll
    for (int f = 0; f < 4; ++f) {
#pragma unroll
      for (int rg = 0; rg < 4; ++rg) {
        float p = __builtin_amdgcn_exp2f(st[f][rg] - mnew);
        rs += p;
        pb[f][rg] = (_Float16)p;
      }
    }
    rs += __shfl_xor(rs, 16);
    rs += __shfl_xor(rs, 32);
    lsum = lsum * corr + rs;
#pragma unroll
    for (int db = 0; db < 4; ++db) ot[db] *= corr;

    // O^T += V^T * P^T : 16x16x16, A-frag from Vs, B-frag = pb (no lane movement)
#pragma unroll
    for (int db = 0; db < 4; ++db) {
      const int vrow = db * 16 + r16;
      const int vs_ = (vrow & 7) << 3;
#pragma unroll
      for (int f = 0; f < 4; ++f) {
        h4 va = *(const h4*)(Vs + vrow * 64 + ((f * 16 + g * 4) ^ vs_));
        ot[db] = __builtin_amdgcn_mfma_f32_16x16x16f16(va, pb[f], ot[db], 0, 0, 0);
      }
    }
  }

  // epilogue: O^T -> LDS (swizzled) -> coalesced 16B global stores
  const float inv = 1.f / lsum;
  __syncthreads();
  _Float16* olds = Ks;
#pragma unroll
  for (int db = 0; db < 4; ++db)
#pragma unroll
    for (int rg = 0; rg < 4; ++rg) {
      const int d = db * 16 + g * 4 + rg;
      olds[qrow * 64 + (d ^ ((qrow & 7) << 3))] = (_Float16)(ot[db][rg] * inv);
    }
  __syncthreads();
  const int bb = bh >> 4, hh = bh & 15;
#pragma unroll
  for (int i = 0; i < 2; ++i) {
    const int idx = tid + i * 256;
    const int q = idx >> 3, c = idx & 7;
    h8 vv = *(const h8*)(olds + q * 64 + ((c ^ (q & 7)) << 3));
    *(h8*)(Oall + ((size_t)(bb * 2048 + q0 + q) * 1024 + hh * 64 + c * 8)) = vv;
  }
}

// ---------------------------------------------------------------- launch
extern "C" void kernel_launch(void* const* d_in, const int* in_sizes, int n_in,
                              void* d_out, int out_size, void* d_ws, size_t ws_size,
                              hipStream_t stream) {
  const float* x     = (const float*)d_in[0];
  const float* w_qkv = (const float*)d_in[1];
  const float* w_out = (const float*)d_in[2];
  const float* b_out = (const float*)d_in[3];
  float* out = (float*)d_out;

  char* ws = (char*)d_ws;
  _Float16* x_h    = (_Float16*)(ws);                    // 8192*1024*2   = 16 MB
  _Float16* wqkv_t = (_Float16*)(ws + 16777216);         // 3072*1024*2   = 6 MB
  _Float16* wout_t = (_Float16*)(ws + 23068672);         // 1024*1024*2   = 2 MB
  _Float16* q_h    = (_Float16*)(ws + 25165824);         // 16 MB  [b,h,n,d]
  _Float16* k_h    = (_Float16*)(ws + 41943040);         // 16 MB  [b,h,n,d]
  _Float16* v_t    = (_Float16*)(ws + 58720256);         // 16 MB  [b,h,d,n]
  _Float16* o_h    = (_Float16*)(ws + 75497472);         // 16 MB  [b,n,h*d]

  hipLaunchKernelGGL(cvt_f32_h, dim3(2048), dim3(256), 0, stream, x, x_h, (8192 * 1024) / 8);
  hipLaunchKernelGGL(transpose_cvt, dim3(96, 32), dim3(256), 0, stream, w_qkv, wqkv_t, 1024, 3072);
  hipLaunchKernelGGL(transpose_cvt, dim3(32, 32), dim3(256), 0, stream, w_out, wout_t, 1024, 1024);

  hipLaunchKernelGGL((gemm_kernel<0>), dim3(64, 24), dim3(256), 0, stream,
                     x_h, wqkv_t, nullptr, nullptr, q_h, k_h, v_t, 3072, 1024);

  hipLaunchKernelGGL(attn_kernel, dim3(2048), dim3(256), 0, stream, q_h, k_h, v_t, o_h);

  hipLaunchKernelGGL((gemm_kernel<1>), dim3(64, 8), dim3(256), 0, stream,
                     o_h, wout_t, out, b_out, nullptr, nullptr, nullptr, 1024, 1024);
}

// Round 2
// 224.121 us; speedup vs baseline: 1.1387x; 1.1387x over previous
//
#include <hip/hip_runtime.h>
#include <hip/hip_fp16.h>

typedef __attribute__((ext_vector_type(4))) float f32x4;
typedef __attribute__((ext_vector_type(8))) _Float16 h8;
typedef __attribute__((ext_vector_type(4))) _Float16 h4;

// ---------------------------------------------------------------- helpers
__device__ __forceinline__ void gld16(const _Float16* g, _Float16* l) {
  __builtin_amdgcn_global_load_lds(
      (const __attribute__((address_space(1))) void*)g,
      (__attribute__((address_space(3))) void*)l, 16, 0, 0);
}

// ---------------------------------------------------------------- convert f32 -> f16 (vectorized)
__global__ void cvt_f32_h(const float* __restrict__ in, _Float16* __restrict__ out, int n8) {
  for (int i = blockIdx.x * blockDim.x + threadIdx.x; i < n8; i += gridDim.x * blockDim.x) {
    const f32x4* p = (const f32x4*)(in + (size_t)i * 8);
    f32x4 a = p[0], b = p[1];
    h8 o;
    o[0] = (_Float16)a[0]; o[1] = (_Float16)a[1]; o[2] = (_Float16)a[2]; o[3] = (_Float16)a[3];
    o[4] = (_Float16)b[0]; o[5] = (_Float16)b[1]; o[6] = (_Float16)b[2]; o[7] = (_Float16)b[3];
    *(h8*)(out + (size_t)i * 8) = o;
  }
}

// ---------------------------------------------------------------- transpose + convert: in[R][C] f32 -> out[C][R] f16
__global__ void transpose_cvt(const float* __restrict__ in, _Float16* __restrict__ out, int R, int C) {
  __shared__ float tile[32][33];
  const int tx = threadIdx.x & 31, ty = threadIdx.x >> 5;
  const int c = blockIdx.x * 32 + tx;
#pragma unroll
  for (int j = 0; j < 32; j += 8) {
    int r = blockIdx.y * 32 + ty + j;
    tile[ty + j][tx] = in[(size_t)r * C + c];
  }
  __syncthreads();
#pragma unroll
  for (int j = 0; j < 32; j += 8) {
    out[(size_t)(blockIdx.x * 32 + ty + j) * R + blockIdx.y * 32 + tx] = (_Float16)tile[tx][ty + j];
  }
}

// ---------------------------------------------------------------- GEMM (unchanged, m97 structure)
template <int EPI>
__global__ __launch_bounds__(256, 2)
void gemm_kernel(const _Float16* __restrict__ A, const _Float16* __restrict__ Bt,
                 float* __restrict__ outF, const float* __restrict__ bias,
                 _Float16* __restrict__ q_h, _Float16* __restrict__ k_h,
                 _Float16* __restrict__ v_t, const int Nn, const int K) {
  __shared__ _Float16 As[128 * 64];
  __shared__ _Float16 Bs[128 * 64];
  const int tid = threadIdx.x;
  const int wid = tid >> 6, lane = tid & 63;
  const int g = lane >> 4, r16 = lane & 15;
  const int wr = wid >> 1, wc = wid & 1;
  const int row0 = blockIdx.x * 128;
  const int col0 = blockIdx.y * 128;
  f32x4 acc[4][4] = {};
  const int sr = tid >> 3, sc = tid & 7;
  const _Float16* ag = A + (size_t)(row0 + sr) * K + sc * 8;
  const _Float16* bg = Bt + (size_t)(col0 + sr) * K + sc * 8;

  for (int kt = 0; kt < K; kt += 64) {
    __syncthreads();
#pragma unroll
    for (int i = 0; i < 4; ++i)
      gld16(ag + (size_t)i * 32 * K + kt, As + i * 2048 + wid * 512);
#pragma unroll
    for (int i = 0; i < 4; ++i)
      gld16(bg + (size_t)i * 32 * K + kt, Bs + i * 2048 + wid * 512);
    __syncthreads();

#pragma unroll
    for (int kk = 0; kk < 2; ++kk) {
      h8 af[4], bf[4];
#pragma unroll
      for (int mt = 0; mt < 4; ++mt)
        af[mt] = *(const h8*)(As + (wr * 64 + mt * 16 + r16) * 64 + kk * 32 + g * 8);
#pragma unroll
      for (int nt = 0; nt < 4; ++nt)
        bf[nt] = *(const h8*)(Bs + (wc * 64 + nt * 16 + r16) * 64 + kk * 32 + g * 8);
#pragma unroll
      for (int mt = 0; mt < 4; ++mt)
#pragma unroll
        for (int nt = 0; nt < 4; ++nt)
          acc[mt][nt] = __builtin_amdgcn_mfma_f32_16x16x32_f16(af[mt], bf[nt], acc[mt][nt], 0, 0, 0);
    }
  }

  if (EPI == 0) {
    const float qscale = 0.125f * 1.44269504088896340736f;  // 1/sqrt(64) * log2(e)
#pragma unroll
    for (int mt = 0; mt < 4; ++mt) {
#pragma unroll
      for (int nt = 0; nt < 4; ++nt) {
        const int j = col0 + wc * 64 + nt * 16 + r16;
        const int which = j >> 10;
        const int hd = j & 1023;
        const int hh = hd >> 6, dd = hd & 63;
#pragma unroll
        for (int rg = 0; rg < 4; ++rg) {
          const int mm = row0 + wr * 64 + mt * 16 + g * 4 + rg;
          const int b = mm >> 11, n = mm & 2047;
          const size_t bh = (size_t)(b * 16 + hh);
          const float v = acc[mt][nt][rg];
          if (which == 0)      q_h[(bh * 2048 + n) * 64 + dd] = (_Float16)(v * qscale);
          else if (which == 1) k_h[(bh * 2048 + n) * 64 + dd] = (_Float16)v;
          else                 v_t[(bh * 64 + dd) * 2048 + n] = (_Float16)v;
        }
      }
    }
  } else {
#pragma unroll
    for (int mt = 0; mt < 4; ++mt) {
#pragma unroll
      for (int nt = 0; nt < 4; ++nt) {
        const int j = col0 + wc * 64 + nt * 16 + r16;
        const float bv = bias[j];
#pragma unroll
        for (int rg = 0; rg < 4; ++rg) {
          const int mm = row0 + wr * 64 + mt * 16 + g * 4 + rg;
          outF[(size_t)mm * Nn + j] = acc[mt][nt][rg] + bv;
        }
      }
    }
  }
}

// ---------------------------------------------------------------- flash attention (v2)
// 4 waves x 64 q-rows = 256 q/block. KV tiles of 64, double-buffered.
// K-frags (8 h8) and V-frags (16 h4) loaded once per tile, reused across 4 q-blocks.
__device__ __forceinline__ void stage_kv(const _Float16* Kg, const _Float16* Vg,
                                         _Float16* KsB, _Float16* VsB,
                                         int kv0, int sr, int sc8, int wid) {
#pragma unroll
  for (int i = 0; i < 2; ++i) {
    int r = i * 32 + sr;
    gld16(Kg + (size_t)(kv0 + r) * 64 + (sc8 ^ ((r & 7) * 8)), KsB + i * 2048 + wid * 512);
    gld16(Vg + (size_t)r * 2048 + kv0 + (sc8 ^ ((r & 7) * 8)), VsB + i * 2048 + wid * 512);
  }
}

__global__ __launch_bounds__(256, 2)
void attn_kernel(const _Float16* __restrict__ Qall, const _Float16* __restrict__ Kall,
                 const _Float16* __restrict__ Vtall, _Float16* __restrict__ Oall) {
  __shared__ _Float16 Qs[256 * 64];     // 32 KB, reused for O epilogue
  __shared__ _Float16 Ks[2][64 * 64];   // 16 KB dbuf
  __shared__ _Float16 Vs[2][64 * 64];   // 16 KB dbuf (V^T: [d][key])
  const int tid = threadIdx.x;
  const int wid = tid >> 6, lane = tid & 63;
  const int g = lane >> 4, r16 = lane & 15;
  // bijective XCD remap: blocks of one (b,h) land on one XCD (8 q-tiles share KV in L2)
  const int blk = (blockIdx.x & 7) * 64 + (blockIdx.x >> 3);
  const int qt = blk & 7;
  const int bh = blk >> 3;
  const _Float16* Qg = Qall + (size_t)bh * (2048 * 64);
  const _Float16* Kg = Kall + (size_t)bh * (2048 * 64);
  const _Float16* Vg = Vtall + (size_t)bh * (2048 * 64);
  const int q0 = qt * 256;
  const int sr = tid >> 3, sc8 = (tid & 7) * 8;

  // prologue: stage Q (256x64, swizzled) + first KV tile
#pragma unroll
  for (int i = 0; i < 8; ++i) {
    int r = i * 32 + sr;
    gld16(Qg + (size_t)(q0 + r) * 64 + (sc8 ^ ((r & 7) * 8)), Qs + i * 2048 + wid * 512);
  }
  stage_kv(Kg, Vg, Ks[0], Vs[0], 0, sr, sc8, wid);
  __syncthreads();

  // Q fragments: 4 q-blocks x (d 0..31, 32..63)
  h8 qf[4][2];
#pragma unroll
  for (int qb = 0; qb < 4; ++qb) {
    const int qrow = wid * 64 + qb * 16 + r16;
#pragma unroll
    for (int kd = 0; kd < 2; ++kd)
      qf[qb][kd] = *(const h8*)(Qs + qrow * 64 + ((kd * 32 + g * 8) ^ ((qrow & 7) * 8)));
  }

  f32x4 ot[4][4] = {};
  float m[4], l[4];
#pragma unroll
  for (int qb = 0; qb < 4; ++qb) { m[qb] = -3.0e38f; l[qb] = 0.f; }

  auto compute = [&](const _Float16* KsB, const _Float16* VsB) {
    h8 kf[4][2];
#pragma unroll
    for (int kb = 0; kb < 4; ++kb) {
      const int krow = kb * 16 + r16;
#pragma unroll
      for (int kd = 0; kd < 2; ++kd)
        kf[kb][kd] = *(const h8*)(KsB + krow * 64 + ((kd * 32 + g * 8) ^ ((krow & 7) * 8)));
    }
    h4 vf[4][4];
#pragma unroll
    for (int db = 0; db < 4; ++db) {
      const int vrow = db * 16 + r16;
#pragma unroll
      for (int kg = 0; kg < 4; ++kg)
        vf[db][kg] = *(const h4*)(VsB + vrow * 64 + ((kg * 16 + g * 4) ^ ((vrow & 7) * 8)));
    }
#pragma unroll
    for (int qb = 0; qb < 4; ++qb) {
      f32x4 st[4];
#pragma unroll
      for (int kb = 0; kb < 4; ++kb) {
        f32x4 s = {};
        s = __builtin_amdgcn_mfma_f32_16x16x32_f16(kf[kb][0], qf[qb][0], s, 0, 0, 0);
        s = __builtin_amdgcn_mfma_f32_16x16x32_f16(kf[kb][1], qf[qb][1], s, 0, 0, 0);
        st[kb] = s;
      }
      float pmax = st[0][0];
#pragma unroll
      for (int kb = 0; kb < 4; ++kb)
#pragma unroll
        for (int rg = 0; rg < 4; ++rg) pmax = fmaxf(pmax, st[kb][rg]);
      pmax = fmaxf(pmax, __shfl_xor(pmax, 16));
      pmax = fmaxf(pmax, __shfl_xor(pmax, 32));
      if (__any(pmax > m[qb] + 8.f)) {   // defer-max: rescale only on real growth
        const float mn = fmaxf(m[qb], pmax);
        const float corr = __builtin_amdgcn_exp2f(m[qb] - mn);
        l[qb] *= corr;
#pragma unroll
        for (int db = 0; db < 4; ++db) ot[qb][db] *= corr;
        m[qb] = mn;
      }
      float rs = 0.f;
      h4 pb[4];
#pragma unroll
      for (int kb = 0; kb < 4; ++kb)
#pragma unroll
        for (int rg = 0; rg < 4; ++rg) {
          float p = __builtin_amdgcn_exp2f(st[kb][rg] - m[qb]);
          rs += p;
          pb[kb][rg] = (_Float16)p;
        }
      rs += __shfl_xor(rs, 16);
      rs += __shfl_xor(rs, 32);
      l[qb] += rs;
#pragma unroll
      for (int db = 0; db < 4; ++db)
#pragma unroll
        for (int kg = 0; kg < 4; ++kg)
          ot[qb][db] = __builtin_amdgcn_mfma_f32_16x16x16f16(vf[db][kg], pb[kg], ot[qb][db], 0, 0, 0);
    }
  };

  // main loop: 32 KV tiles, dbuf: issue next stage, compute current, single barrier
#pragma unroll 1
  for (int tt = 0; tt < 16; ++tt) {
    stage_kv(Kg, Vg, Ks[1], Vs[1], (tt * 2 + 1) * 64, sr, sc8, wid);
    compute(Ks[0], Vs[0]);
    __syncthreads();
    if (tt < 15) stage_kv(Kg, Vg, Ks[0], Vs[0], (tt * 2 + 2) * 64, sr, sc8, wid);
    compute(Ks[1], Vs[1]);
    __syncthreads();
  }

  // epilogue: O^T -> Qs (swizzled) -> coalesced 16B stores
#pragma unroll
  for (int qb = 0; qb < 4; ++qb) {
    const float inv = 1.f / l[qb];
    const int qrow = wid * 64 + qb * 16 + r16;
    const int x = (qrow & 7) * 8;
#pragma unroll
    for (int db = 0; db < 4; ++db) {
      h4 o;
#pragma unroll
      for (int rg = 0; rg < 4; ++rg) o[rg] = (_Float16)(ot[qb][db][rg] * inv);
      *(h4*)(Qs + qrow * 64 + ((db * 16 + g * 4) ^ x)) = o;
    }
  }
  __syncthreads();
  const int bb = bh >> 4, hh = bh & 15;
#pragma unroll
  for (int i = 0; i < 8; ++i) {
    const int idx = tid + i * 256;
    const int q = idx >> 3, c = idx & 7;
    h8 vv = *(const h8*)(Qs + q * 64 + ((c * 8) ^ ((q & 7) * 8)));
    *(h8*)(Oall + ((size_t)(bb * 2048 + q0 + q) * 1024 + hh * 64 + c * 8)) = vv;
  }
}

// ---------------------------------------------------------------- launch
extern "C" void kernel_launch(void* const* d_in, const int* in_sizes, int n_in,
                              void* d_out, int out_size, void* d_ws, size_t ws_size,
                              hipStream_t stream) {
  const float* x     = (const float*)d_in[0];
  const float* w_qkv = (const float*)d_in[1];
  const float* w_out = (const float*)d_in[2];
  const float* b_out = (const float*)d_in[3];
  float* out = (float*)d_out;

  char* ws = (char*)d_ws;
  _Float16* x_h    = (_Float16*)(ws);                    // 16 MB
  _Float16* wqkv_t = (_Float16*)(ws + 16777216);         // 6 MB
  _Float16* wout_t = (_Float16*)(ws + 23068672);         // 2 MB
  _Float16* q_h    = (_Float16*)(ws + 25165824);         // 16 MB [b,h,n,d] (pre-scaled)
  _Float16* k_h    = (_Float16*)(ws + 41943040);         // 16 MB [b,h,n,d]
  _Float16* v_t    = (_Float16*)(ws + 58720256);         // 16 MB [b,h,d,n]
  _Float16* o_h    = (_Float16*)(ws + 75497472);         // 16 MB [b,n,h*d]

  hipLaunchKernelGGL(cvt_f32_h, dim3(2048), dim3(256), 0, stream, x, x_h, (8192 * 1024) / 8);
  hipLaunchKernelGGL(transpose_cvt, dim3(96, 32), dim3(256), 0, stream, w_qkv, wqkv_t, 1024, 3072);
  hipLaunchKernelGGL(transpose_cvt, dim3(32, 32), dim3(256), 0, stream, w_out, wout_t, 1024, 1024);

  hipLaunchKernelGGL((gemm_kernel<0>), dim3(64, 24), dim3(256), 0, stream,
                     x_h, wqkv_t, nullptr, nullptr, q_h, k_h, v_t, 3072, 1024);

  hipLaunchKernelGGL(attn_kernel, dim3(512), dim3(256), 0, stream, q_h, k_h, v_t, o_h);

  hipLaunchKernelGGL((gemm_kernel<1>), dim3(64, 8), dim3(256), 0, stream,
                     o_h, wout_t, out, b_out, nullptr, nullptr, nullptr, 1024, 1024);
}